// Round 1
// 745.051 us; speedup vs baseline: 1.0056x; 1.0056x over previous
//
#include <hip/hip_runtime.h>
#include <cstdint>
#include <cstddef>

#define D_MODEL 2048
#define D_FFN   8192
#define RANK    16
#define EPS     1e-6f
#define MOD_SCALE 0.1f

typedef float    f32x4 __attribute__((ext_vector_type(4)));
typedef _Float16 half8 __attribute__((ext_vector_type(8)));

// Async global->LDS, 16B per lane. LDS dest is wave-uniform base + lane*16;
// the GLOBAL address is per-lane, so we XOR-swizzle the source 16B chunk
// (c ^ (row&7)) for bank-conflict-free ds_read_b128 later, at zero cost.
// R3-proven: conflict-free ONLY with the 16x16 quad-based fragment addressing
// (frag64 below). Geometry everywhere: 64-half (128 B) row stride.
__device__ __forceinline__ void async_load16(const void* g, void* l) {
  __builtin_amdgcn_global_load_lds(
      (const __attribute__((address_space(1))) uint32_t*)g,
      (__attribute__((address_space(3))) uint32_t*)l,
      16, 0, 0);
}

// Stage one 64-row x 64-half (8 KB) round; 512 threads x 16 B.
__device__ __forceinline__ void stage_round(const _Float16* __restrict__ g,
                                            size_t stride, _Float16* l, int tid) {
  const int row = tid >> 3;
  const int cs  = (tid & 7) ^ (row & 7);
  async_load16(g + (size_t)row * stride + (size_t)cs * 8, l + tid * 8);
}

// Read 8-half fragment at (row, 8-half chunk ck) from a swizzled 64-wide tile.
__device__ __forceinline__ half8 frag64(const _Float16* base, int row, int ck) {
  return *(const half8*)&base[row * 64 + ((ck ^ (row & 7)) * 8)];
}

#define BAR()   __builtin_amdgcn_s_barrier()
#define PRIO1() __builtin_amdgcn_s_setprio(1)
#define PRIO0() __builtin_amdgcn_s_setprio(0)
#define VMW(n)  asm volatile("s_waitcnt vmcnt(" #n ")" ::: "memory")

// ---------------------------------------------------------------------------
// Fused fp32 -> f16 convert for all three big weights (one launch).
// ---------------------------------------------------------------------------
__global__ __launch_bounds__(256) void convert3_f32_f16(
    const float* __restrict__ s0, const float* __restrict__ s1,
    const float* __restrict__ s2,
    _Float16* __restrict__ d0, _Float16* __restrict__ d1,
    _Float16* __restrict__ d2)
{
  const int w = blockIdx.x >> 13;
  const float*   s = (w == 0) ? s0 : (w == 1) ? s1 : s2;
  _Float16*      d = (w == 0) ? d0 : (w == 1) ? d1 : d2;
  size_t i = ((size_t)(blockIdx.x & 8191) * 256 + threadIdx.x) * 8;
  f32x4 a = *(const f32x4*)(s + i);
  f32x4 b = *(const f32x4*)(s + i + 4);
  half8 h;
  #pragma unroll
  for (int j = 0; j < 4; ++j) { h[j] = (_Float16)a[j]; h[4+j] = (_Float16)b[j]; }
  *(half8*)(d + i) = h;
}

__global__ __launch_bounds__(256) void convert_f32_f16(
    const float* __restrict__ s, _Float16* __restrict__ d)
{
  size_t i = ((size_t)blockIdx.x * 256 + threadIdx.x) * 8;
  f32x4 a = *(const f32x4*)(s + i);
  f32x4 b = *(const f32x4*)(s + i + 4);
  half8 h;
  #pragma unroll
  for (int j = 0; j < 4; ++j) { h[j] = (_Float16)a[j]; h[4+j] = (_Float16)b[j]; }
  *(half8*)(d + i) = h;
}

// ---------------------------------------------------------------------------
// Kernel 1: per-token RMSNorm -> h (f16), c[m,r] = (h.A)[r] * 0.1*tanh((attn.A)[r])
// ---------------------------------------------------------------------------
__global__ __launch_bounds__(256) void prep_kernel(
    const float* __restrict__ hs, const float* __restrict__ attn,
    const float* __restrict__ Amat, const float* __restrict__ gamma,
    _Float16* __restrict__ h16, float* __restrict__ cmat)
{
  const int token = blockIdx.x;
  const int tid   = threadIdx.x;
  const int lane  = tid & 63;
  const int wv    = tid >> 6;
  const size_t tb = (size_t)token * D_MODEL;
  const int base  = tid * 8;

  f32x4 x0 = *(const f32x4*)(hs + tb + base);
  f32x4 x1 = *(const f32x4*)(hs + tb + base + 4);
  f32x4 a0 = *(const f32x4*)(attn + tb + base);
  f32x4 a1 = *(const f32x4*)(attn + tb + base + 4);

  float ss = 0.f;
  #pragma unroll
  for (int j = 0; j < 4; ++j) ss += x0[j]*x0[j] + x1[j]*x1[j];
  #pragma unroll
  for (int off = 32; off > 0; off >>= 1) ss += __shfl_xor(ss, off, 64);

  __shared__ float red[4];
  __shared__ float redp[4][RANK];
  __shared__ float redh[4][RANK];
  if (lane == 0) red[wv] = ss;
  __syncthreads();
  const float tot = red[0] + red[1] + red[2] + red[3];
  const float rms = rsqrtf(tot * (1.0f / D_MODEL) + EPS);

  f32x4 g0 = *(const f32x4*)(gamma + base);
  f32x4 g1 = *(const f32x4*)(gamma + base + 4);
  float hv[8], av[8];
  #pragma unroll
  for (int j = 0; j < 4; ++j) {
    hv[j]   = x0[j] * rms * g0[j];
    hv[4+j] = x1[j] * rms * g1[j];
    av[j]   = a0[j];
    av[4+j] = a1[j];
  }
  half8 hh;
  #pragma unroll
  for (int j = 0; j < 8; ++j) hh[j] = (_Float16)hv[j];
  *(half8*)(h16 + tb + base) = hh;

  float pa[RANK], ph[RANK];
  #pragma unroll
  for (int r = 0; r < RANK; ++r) { pa[r] = 0.f; ph[r] = 0.f; }
  #pragma unroll
  for (int e = 0; e < 8; ++e) {
    const f32x4* Ar = (const f32x4*)(Amat + (size_t)(base + e) * RANK);
    #pragma unroll
    for (int q = 0; q < 4; ++q) {
      f32x4 ar = Ar[q];
      #pragma unroll
      for (int j = 0; j < 4; ++j) {
        pa[q*4+j] += av[e] * ar[j];
        ph[q*4+j] += hv[e] * ar[j];
      }
    }
  }
  #pragma unroll
  for (int r = 0; r < RANK; ++r) {
    #pragma unroll
    for (int off = 32; off > 0; off >>= 1) {
      pa[r] += __shfl_xor(pa[r], off, 64);
      ph[r] += __shfl_xor(ph[r], off, 64);
    }
  }
  if (lane == 0) {
    #pragma unroll
    for (int r = 0; r < RANK; ++r) { redp[wv][r] = pa[r]; redh[wv][r] = ph[r]; }
  }
  __syncthreads();
  if (tid < RANK) {
    float sp = redp[0][tid] + redp[1][tid] + redp[2][tid] + redp[3][tid];
    float sh = redh[0][tid] + redh[1][tid] + redh[2][tid] + redh[3][tid];
    cmat[(size_t)token * RANK + tid] = sh * (MOD_SCALE * tanhf(sp));
  }
}

// ---------------------------------------------------------------------------
// Kernel 2: dual GEMM, 256x128 tile, BK=64, 8 waves (2M x 4N), 4-phase
// counted-vmcnt pipeline (T3+T4) + setprio (T5).
//
// LDS per buffer (halves): A quarters q0..q3 [64][64] at q*4096 (rows gm0+q*64),
//   Bg pairs at 16384+p*4096, Bu pairs at 24576+p*4096 (pair p = weight rows
//   gn0+p*64..+63 = sub-tiles 2p,2p+1 of [32][64]). 2 buffers = 128 KB.
//
// Phase layout per K-step t (buf cur=t&1): P1 rows(rm0) x gate, P2 rows(rm0) x up,
//   P3 rows(rm1) x gate, P4 rows(rm1) x up. LDS region last reads: A-even P1,
//   Bg P1 (regs held for P3), Bu P2, A-odd P3.
// Stage slots (derived, stage-phase > last-read of 2-tiles-ago occupant,
//   landing forced >=3 phases later):
//   P1: Bu(t+1)->nxt   P2: A-odd(t+1)->nxt   P3: A-even(t+2)->cur   P4: Bg(t+2)->cur
// Waits: vmcnt(8) at end of P1, P2, P4 (steady in-flight = 4 slots = 8 loads,
//   NEVER drained to 0 while t+3<NT). Verified slot-by-slot:
//   endP4(t-1) drains A-even(t)+Bg(t); endP1(t) drains Bu(t); endP2(t) drains A-odd(t).
// ---------------------------------------------------------------------------
#define BGOFF 16384
#define BUOFF 24576

__global__ __launch_bounds__(512, 2) void gemm_gateup(
    const _Float16* __restrict__ h16,
    const _Float16* __restrict__ Wg16, const _Float16* __restrict__ Wu16,
    const float* __restrict__ cmat, const float* __restrict__ Bmat,
    _Float16* __restrict__ tmat)
{
  __shared__ __align__(16) _Float16 lds[2][32768];   // 128 KB

  const int tid  = threadIdx.x;
  const int lane = tid & 63;
  const int wv   = tid >> 6;          // 0..7
  const int lr   = lane & 15;
  const int quad = lane >> 4;
  const int qb   = (wv >> 2) * 2;     // A quarter base: 0 or 2
  const int e    = wv & 3;            // B sub-tile (32 cols)
  const int wm   = (wv >> 2) * 128;   // wave row base in tile

  // XCD-aware swizzle over m-fastest linearization (1024 % 8 == 0, bijective)
  const int lin = blockIdx.x;
  const int swz = (lin & 7) * 128 + (lin >> 3);
  const int gm0 = (swz & 15) * 256;   // 16 m-tiles
  const int gn0 = (swz >> 4) * 128;   // 64 n-tiles

  constexpr int NT = D_MODEL / 64;    // 32

  f32x4 accG[8][2], accU[8][2];
  #pragma unroll
  for (int i = 0; i < 8; ++i)
    #pragma unroll
    for (int j = 0; j < 2; ++j) {
      f32x4 z = {0.f, 0.f, 0.f, 0.f};
      accG[i][j] = z; accU[i][j] = z;
    }

#define STA(b,q,t)  stage_round(h16  + (size_t)(gm0 + (q)*64) * D_MODEL + (size_t)(t)*64, D_MODEL, &lds[b][(q)*4096], tid)
#define STBG(b,p,t) stage_round(Wg16 + (size_t)(gn0 + (p)*64) * D_MODEL + (size_t)(t)*64, D_MODEL, &lds[b][BGOFF + (p)*4096], tid)
#define STBU(b,p,t) stage_round(Wu16 + (size_t)(gn0 + (p)*64) * D_MODEL + (size_t)(t)*64, D_MODEL, &lds[b][BUOFF + (p)*4096], tid)

  // Prologue: A-even(0), Bg(0), Bu(0), A-odd(0), A-even(1), Bg(1) = 12 loads;
  // wait to 8 -> tile-0 first-phase needs landed, 4 newest slots stay in flight.
  STA(0,0,0);  STA(0,2,0);
  STBG(0,0,0); STBG(0,1,0);
  STBU(0,0,0); STBU(0,1,0);
  STA(0,1,0);  STA(0,3,0);
  STA(1,0,1);  STA(1,2,1);
  STBG(1,0,1); STBG(1,1,1);
  VMW(8); BAR();

  half8 af[4][2], bg[2][2], bu[2][2];

  for (int t = 0; t < NT; ++t) {
    const int cur = t & 1, nxt = cur ^ 1;
    const _Float16* A   = &lds[cur][0];
    const _Float16* Bgp = &lds[cur][BGOFF + e * 2048];
    const _Float16* Bup = &lds[cur][BUOFF + e * 2048];
    const bool s1 = (t + 1 < NT);
    const bool s2 = (t + 2 < NT);
    const bool deep = (t + 3 < NT);

    // ---------------- Phase 1: rows rm0 x gate ----------------
    #pragma unroll
    for (int im = 0; im < 4; ++im)
      #pragma unroll
      for (int kk = 0; kk < 2; ++kk)
        af[im][kk] = frag64(A + (qb + 0) * 4096, im*16 + lr, kk*4 + quad);
    #pragma unroll
    for (int inn = 0; inn < 2; ++inn)
      #pragma unroll
      for (int kk = 0; kk < 2; ++kk)
        bg[inn][kk] = frag64(Bgp, inn*16 + lr, kk*4 + quad);
    if (s1) { STBU(nxt, 0, t+1); STBU(nxt, 1, t+1); }
    BAR();
    PRIO1();
    #pragma unroll
    for (int im = 0; im < 4; ++im)
      #pragma unroll
      for (int inn = 0; inn < 2; ++inn)
        #pragma unroll
        for (int kk = 0; kk < 2; ++kk)
          accG[im][inn] = __builtin_amdgcn_mfma_f32_16x16x32_f16(af[im][kk], bg[inn][kk], accG[im][inn], 0, 0, 0);
    PRIO0();
    if (deep) { VMW(8); } else { VMW(0); }
    BAR();

    // ---------------- Phase 2: rows rm0 x up ----------------
    #pragma unroll
    for (int inn = 0; inn < 2; ++inn)
      #pragma unroll
      for (int kk = 0; kk < 2; ++kk)
        bu[inn][kk] = frag64(Bup, inn*16 + lr, kk*4 + quad);
    if (s1) { STA(nxt, 1, t+1); STA(nxt, 3, t+1); }
    BAR();
    PRIO1();
    #pragma unroll
    for (int im = 0; im < 4; ++im)
      #pragma unroll
      for (int inn = 0; inn < 2; ++inn)
        #pragma unroll
        for (int kk = 0; kk < 2; ++kk)
          accU[im][inn] = __builtin_amdgcn_mfma_f32_16x16x32_f16(af[im][kk], bu[inn][kk], accU[im][inn], 0, 0, 0);
    PRIO0();
    if (deep) { VMW(8); } else { VMW(0); }
    BAR();

    // ---------------- Phase 3: rows rm1 x gate (bg held in regs) ----------------
    #pragma unroll
    for (int im = 0; im < 4; ++im)
      #pragma unroll
      for (int kk = 0; kk < 2; ++kk)
        af[im][kk] = frag64(A + (qb + 1) * 4096, im*16 + lr, kk*4 + quad);
    if (s2) { STA(cur, 0, t+2); STA(cur, 2, t+2); }
    BAR();
    PRIO1();
    #pragma unroll
    for (int im = 0; im < 4; ++im)
      #pragma unroll
      for (int inn = 0; inn < 2; ++inn)
        #pragma unroll
        for (int kk = 0; kk < 2; ++kk)
          accG[4+im][inn] = __builtin_amdgcn_mfma_f32_16x16x32_f16(af[im][kk], bg[inn][kk], accG[4+im][inn], 0, 0, 0);
    PRIO0();
    BAR();

    // ---------------- Phase 4: rows rm1 x up (af, bu held) ----------------
    if (s2) { STBG(cur, 0, t+2); STBG(cur, 1, t+2); }
    BAR();
    PRIO1();
    #pragma unroll
    for (int im = 0; im < 4; ++im)
      #pragma unroll
      for (int inn = 0; inn < 2; ++inn)
        #pragma unroll
        for (int kk = 0; kk < 2; ++kk)
          accU[4+im][inn] = __builtin_amdgcn_mfma_f32_16x16x32_f16(af[im][kk], bu[inn][kk], accU[4+im][inn], 0, 0, 0);
    PRIO0();
    if (deep) { VMW(8); } else { VMW(0); }
    BAR();
  }

  // ---- rank-16 delta folded in as one zero-padded K=32 MFMA step into accG ----
  __syncthreads();   // drains everything; loop is done
  _Float16* l0 = &lds[0][0];
  for (int i = tid; i < 8192; i += 512) {           // cbuf [256][32]
    int m = i >> 5, k = i & 31;
    l0[i] = (k < RANK) ? (_Float16)cmat[(size_t)(gm0 + m) * RANK + k] : (_Float16)0.f;
  }
  for (int i = tid; i < 4096; i += 512) {           // bbuf [128][32]
    int f = i >> 5, k = i & 31;
    l0[8192 + i] = (k < RANK) ? (_Float16)Bmat[(size_t)k * D_FFN + gn0 + f] : (_Float16)0.f;
  }
  __syncthreads();
  #pragma unroll
  for (int ai = 0; ai < 8; ++ai) {
    half8 cf = *(const half8*)&l0[(wm + ai*16 + lr) * 32 + quad * 8];
    #pragma unroll
    for (int inn = 0; inn < 2; ++inn) {
      half8 bd = *(const half8*)&l0[8192 + (e*32 + inn*16 + lr) * 32 + quad * 8];
      accG[ai][inn] = __builtin_amdgcn_mfma_f32_16x16x32_f16(cf, bd, accG[ai][inn], 0, 0, 0);
    }
  }

  // ---- Epilogue: t = silu(gate) * up ----
  #pragma unroll
  for (int ai = 0; ai < 8; ++ai)
    #pragma unroll
    for (int inn = 0; inn < 2; ++inn) {
      const int grow = gm0 + wm + ai*16 + quad*4;
      const int gcol = gn0 + e*32 + inn*16 + lr;
      #pragma unroll
      for (int r = 0; r < 4; ++r) {
        float g = accG[ai][inn][r];
        float u = accU[ai][inn][r];
        float s = g / (1.0f + __expf(-g));
        tmat[(size_t)(grow + r) * D_FFN + gcol] = (_Float16)(s * u);
      }
    }
#undef STA
#undef STBG
#undef STBU
}

// ---------------------------------------------------------------------------
// Kernel 3: out = hidden_states + t @ Wd16^T (K=8192). 256x128 tile, BK=64,
// 3-buffer rotation (144 KB LDS): tile t+2 staged into a fully-free buffer
// during pass t -> 2-pass lookahead, single vmcnt(6) per K-step (never 0
// while t+3<NT). 2 phases x 16 MFMA, setprio around each cluster.
// Grid = exactly 256 blocks (1 per CU).
// ---------------------------------------------------------------------------
__global__ __launch_bounds__(512, 2) void gemm_down(
    const _Float16* __restrict__ tmat, const _Float16* __restrict__ Wd16,
    const float* __restrict__ hs, float* __restrict__ out)
{
  __shared__ __align__(16) _Float16 lds[3][24576];   // 144 KB: A 16K halves | B 8K halves

  const int tid  = threadIdx.x;
  const int lane = tid & 63;
  const int wv   = tid >> 6;
  const int lr   = lane & 15;
  const int quad = lane >> 4;
  const int qb   = (wv >> 2) * 2;
  const int e    = wv & 3;
  const int wm   = (wv >> 2) * 128;

  const int lin = blockIdx.x;             // 256 blocks, 256 % 8 == 0
  const int swz = (lin & 7) * 32 + (lin >> 3);
  const int gm0 = (swz & 15) * 256;       // 16 m-tiles
  const int gn0 = (swz >> 4) * 128;       // 16 n-tiles

  constexpr int NT = D_FFN / 64;          // 128

  f32x4 acc[8][2];
  #pragma unroll
  for (int i = 0; i < 8; ++i)
    #pragma unroll
    for (int j = 0; j < 2; ++j) {
      f32x4 z = {0.f, 0.f, 0.f, 0.f};
      acc[i][j] = z;
    }

#define DSTA(b,q,t) stage_round(tmat + (size_t)(gm0 + (q)*64) * D_FFN + (size_t)(t)*64, D_FFN, &lds[b][(q)*4096], tid)
#define DSTB(b,p,t) stage_round(Wd16 + (size_t)(gn0 + (p)*64) * D_FFN + (size_t)(t)*64, D_FFN, &lds[b][16384 + (p)*4096], tid)

  // Prologue: tiles 0 and 1 (6 loads each); wait to 6 -> tile 0 landed.
  DSTA(0,0,0); DSTA(0,1,0); DSTA(0,2,0); DSTA(0,3,0); DSTB(0,0,0); DSTB(0,1,0);
  DSTA(1,0,1); DSTA(1,1,1); DSTA(1,2,1); DSTA(1,3,1); DSTB(1,0,1); DSTB(1,1,1);
  VMW(6); BAR();

  half8 af[4][2], bf[2][2];
  int cur = 0;

  for (int t = 0; t < NT; ++t) {
    const _Float16* A = &lds[cur][0];
    const _Float16* B = &lds[cur][16384 + e * 2048];
    int nx2 = cur + 2; if (nx2 >= 3) nx2 -= 3;     // buffer for tile t+2
    const bool s2 = (t + 2 < NT);
    const bool deep = (t + 3 < NT);

    // ---------------- Phase 1: rows rm0 ----------------
    #pragma unroll
    for (int im = 0; im < 4; ++im)
      #pragma unroll
      for (int kk = 0; kk < 2; ++kk)
        af[im][kk] = frag64(A + (qb + 0) * 4096, im*16 + lr, kk*4 + quad);
    #pragma unroll
    for (int inn = 0; inn < 2; ++inn)
      #pragma unroll
      for (int kk = 0; kk < 2; ++kk)
        bf[inn][kk] = frag64(B, inn*16 + lr, kk*4 + quad);
    if (s2) { DSTA(nx2, 0, t+2); DSTA(nx2, 2, t+2); DSTB(nx2, 0, t+2); }
    BAR();
    PRIO1();
    #pragma unroll
    for (int im = 0; im < 4; ++im)
      #pragma unroll
      for (int inn = 0; inn < 2; ++inn)
        #pragma unroll
        for (int kk = 0; kk < 2; ++kk)
          acc[im][inn] = __builtin_amdgcn_mfma_f32_16x16x32_f16(af[im][kk], bf[inn][kk], acc[im][inn], 0, 0, 0);
    PRIO0();
    BAR();

    // ---------------- Phase 2: rows rm1 (bf held in regs) ----------------
    #pragma unroll
    for (int im = 0; im < 4; ++im)
      #pragma unroll
      for (int kk = 0; kk < 2; ++kk)
        af[im][kk] = frag64(A + (qb + 1) * 4096, im*16 + lr, kk*4 + quad);
    if (s2) { DSTA(nx2, 1, t+2); DSTA(nx2, 3, t+2); DSTB(nx2, 1, t+2); }
    BAR();
    PRIO1();
    #pragma unroll
    for (int im = 0; im < 4; ++im)
      #pragma unroll
      for (int inn = 0; inn < 2; ++inn)
        #pragma unroll
        for (int kk = 0; kk < 2; ++kk)
          acc[4+im][inn] = __builtin_amdgcn_mfma_f32_16x16x32_f16(af[im][kk], bf[inn][kk], acc[4+im][inn], 0, 0, 0);
    PRIO0();
    if (deep) { VMW(6); } else { VMW(0); }   // drains tile t+1; tile t+2 stays in flight
    BAR();

    cur += 1; if (cur >= 3) cur -= 3;
  }

  #pragma unroll
  for (int ai = 0; ai < 8; ++ai)
    #pragma unroll
    for (int inn = 0; inn < 2; ++inn) {
      const int grow = gm0 + wm + ai*16 + quad*4;
      const int gcol = gn0 + e*32 + inn*16 + lr;
      #pragma unroll
      for (int r = 0; r < 4; ++r) {
        size_t o = (size_t)(grow + r) * D_MODEL + gcol;
        out[o] = hs[o] + acc[ai][inn][r];
      }
    }
#undef DSTA
#undef DSTB
}

extern "C" void kernel_launch(void* const* d_in, const int* in_sizes, int n_in,
                              void* d_out, int out_size, void* d_ws, size_t ws_size,
                              hipStream_t stream) {
  const float* hs    = (const float*)d_in[0];
  const float* attn  = (const float*)d_in[1];
  const float* Amat  = (const float*)d_in[2];
  const float* Bmat  = (const float*)d_in[3];
  const float* Wg    = (const float*)d_in[4];
  const float* Wu    = (const float*)d_in[5];
  const float* Wd    = (const float*)d_in[6];
  const float* gamma = (const float*)d_in[7];
  float* out = (float*)d_out;

  const int M = in_sizes[0] / D_MODEL;        // 4096 tokens
  const size_t WD = (size_t)D_FFN * D_MODEL;  // elements per big weight

  char* ws = (char*)d_ws;
  _Float16* h16  = (_Float16*)ws;
  float*    cmat = (float*)(ws + (size_t)M * D_MODEL * 2);
  _Float16* tmat = (_Float16*)(ws + (size_t)M * D_MODEL * 2 + (size_t)M * RANK * 4);
  _Float16* wbuf = tmat + (size_t)M * D_FFN;
  _Float16* Wg16 = wbuf;
  _Float16* Wu16 = wbuf + WD;

  const size_t base_bytes = (size_t)M * D_MODEL * 2 + (size_t)M * RANK * 4
                          + (size_t)M * D_FFN * 2 + 2 * WD * 2;
  const bool sep_wd = (ws_size >= base_bytes + WD * 2);
  _Float16* Wd16 = sep_wd ? (wbuf + 2 * WD) : wbuf;   // else reuse Wg16 slot

  const int convBlocks = (int)(WD / (256 * 8));   // 8192 per weight

  prep_kernel<<<M, 256, 0, stream>>>(hs, attn, Amat, gamma, h16, cmat);
  if (sep_wd) {
    convert3_f32_f16<<<3 * convBlocks, 256, 0, stream>>>(Wg, Wu, Wd, Wg16, Wu16, Wd16);
    gemm_gateup<<<dim3((D_FFN / 128) * (M / 256)), 512, 0, stream>>>(h16, Wg16, Wu16, cmat, Bmat, tmat);
  } else {
    convert_f32_f16<<<convBlocks, 256, 0, stream>>>(Wg, Wg16);
    convert_f32_f16<<<convBlocks, 256, 0, stream>>>(Wu, Wu16);
    gemm_gateup<<<dim3((D_FFN / 128) * (M / 256)), 512, 0, stream>>>(h16, Wg16, Wu16, cmat, Bmat, tmat);
    convert_f32_f16<<<convBlocks, 256, 0, stream>>>(Wd, Wd16);
  }
  gemm_down<<<dim3((D_MODEL / 128) * (M / 256)), 512, 0, stream>>>(tmat, Wd16, hs, out);
}

// Round 2
// 734.687 us; speedup vs baseline: 1.0198x; 1.0141x over previous
//
#include <hip/hip_runtime.h>
#include <cstdint>
#include <cstddef>

#define D_MODEL 2048
#define D_FFN   8192
#define RANK    16
#define EPS     1e-6f
#define MOD_SCALE 0.1f

typedef float    f32x4 __attribute__((ext_vector_type(4)));
typedef _Float16 half8 __attribute__((ext_vector_type(8)));

// Async global->LDS, 16B per lane. LDS dest is wave-uniform base + lane*16;
// the GLOBAL address is per-lane, so we XOR-swizzle the source 16B chunk
// (c ^ (row&7)) for bank-conflict-free ds_read_b128 later, at zero cost.
// R3-proven: conflict-free ONLY with the 16x16 quad-based fragment addressing
// (frag64 below). Geometry everywhere: 64-half (128 B) row stride.
__device__ __forceinline__ void async_load16(const void* g, void* l) {
  __builtin_amdgcn_global_load_lds(
      (const __attribute__((address_space(1))) uint32_t*)g,
      (__attribute__((address_space(3))) uint32_t*)l,
      16, 0, 0);
}

// Stage one 64-row x 64-half (8 KB) round; 512 threads x 16 B.
__device__ __forceinline__ void stage_round(const _Float16* __restrict__ g,
                                            size_t stride, _Float16* l, int tid) {
  const int row = tid >> 3;
  const int cs  = (tid & 7) ^ (row & 7);
  async_load16(g + (size_t)row * stride + (size_t)cs * 8, l + tid * 8);
}

// Read 8-half fragment at (row, 8-half chunk ck) from a swizzled 64-wide tile.
__device__ __forceinline__ half8 frag64(const _Float16* base, int row, int ck) {
  return *(const half8*)&base[row * 64 + ((ck ^ (row & 7)) * 8)];
}

#define PRIO1() __builtin_amdgcn_s_setprio(1)
#define PRIO0() __builtin_amdgcn_s_setprio(0)
#define VMW(n)  asm volatile("s_waitcnt vmcnt(" #n ")" ::: "memory")
// Raw barrier WITH compiler memory fence (no waitcnt drain emitted, unlike
// __syncthreads): no LDS/global op may be moved across it by the scheduler.
#define BARM()  asm volatile("s_barrier" ::: "memory")

// ---------------------------------------------------------------------------
// Fused fp32 -> f16 convert for all three big weights (one launch).
// ---------------------------------------------------------------------------
__global__ __launch_bounds__(256) void convert3_f32_f16(
    const float* __restrict__ s0, const float* __restrict__ s1,
    const float* __restrict__ s2,
    _Float16* __restrict__ d0, _Float16* __restrict__ d1,
    _Float16* __restrict__ d2)
{
  const int w = blockIdx.x >> 13;
  const float*   s = (w == 0) ? s0 : (w == 1) ? s1 : s2;
  _Float16*      d = (w == 0) ? d0 : (w == 1) ? d1 : d2;
  size_t i = ((size_t)(blockIdx.x & 8191) * 256 + threadIdx.x) * 8;
  f32x4 a = *(const f32x4*)(s + i);
  f32x4 b = *(const f32x4*)(s + i + 4);
  half8 h;
  #pragma unroll
  for (int j = 0; j < 4; ++j) { h[j] = (_Float16)a[j]; h[4+j] = (_Float16)b[j]; }
  *(half8*)(d + i) = h;
}

__global__ __launch_bounds__(256) void convert_f32_f16(
    const float* __restrict__ s, _Float16* __restrict__ d)
{
  size_t i = ((size_t)blockIdx.x * 256 + threadIdx.x) * 8;
  f32x4 a = *(const f32x4*)(s + i);
  f32x4 b = *(const f32x4*)(s + i + 4);
  half8 h;
  #pragma unroll
  for (int j = 0; j < 4; ++j) { h[j] = (_Float16)a[j]; h[4+j] = (_Float16)b[j]; }
  *(half8*)(d + i) = h;
}

// ---------------------------------------------------------------------------
// Kernel 1: per-token RMSNorm -> h (f16), c[m,r] = (h.A)[r] * 0.1*tanh((attn.A)[r])
// ---------------------------------------------------------------------------
__global__ __launch_bounds__(256) void prep_kernel(
    const float* __restrict__ hs, const float* __restrict__ attn,
    const float* __restrict__ Amat, const float* __restrict__ gamma,
    _Float16* __restrict__ h16, float* __restrict__ cmat)
{
  const int token = blockIdx.x;
  const int tid   = threadIdx.x;
  const int lane  = tid & 63;
  const int wv    = tid >> 6;
  const size_t tb = (size_t)token * D_MODEL;
  const int base  = tid * 8;

  f32x4 x0 = *(const f32x4*)(hs + tb + base);
  f32x4 x1 = *(const f32x4*)(hs + tb + base + 4);
  f32x4 a0 = *(const f32x4*)(attn + tb + base);
  f32x4 a1 = *(const f32x4*)(attn + tb + base + 4);

  float ss = 0.f;
  #pragma unroll
  for (int j = 0; j < 4; ++j) ss += x0[j]*x0[j] + x1[j]*x1[j];
  #pragma unroll
  for (int off = 32; off > 0; off >>= 1) ss += __shfl_xor(ss, off, 64);

  __shared__ float red[4];
  __shared__ float redp[4][RANK];
  __shared__ float redh[4][RANK];
  if (lane == 0) red[wv] = ss;
  __syncthreads();
  const float tot = red[0] + red[1] + red[2] + red[3];
  const float rms = rsqrtf(tot * (1.0f / D_MODEL) + EPS);

  f32x4 g0 = *(const f32x4*)(gamma + base);
  f32x4 g1 = *(const f32x4*)(gamma + base + 4);
  float hv[8], av[8];
  #pragma unroll
  for (int j = 0; j < 4; ++j) {
    hv[j]   = x0[j] * rms * g0[j];
    hv[4+j] = x1[j] * rms * g1[j];
    av[j]   = a0[j];
    av[4+j] = a1[j];
  }
  half8 hh;
  #pragma unroll
  for (int j = 0; j < 8; ++j) hh[j] = (_Float16)hv[j];
  *(half8*)(h16 + tb + base) = hh;

  float pa[RANK], ph[RANK];
  #pragma unroll
  for (int r = 0; r < RANK; ++r) { pa[r] = 0.f; ph[r] = 0.f; }
  #pragma unroll
  for (int e = 0; e < 8; ++e) {
    const f32x4* Ar = (const f32x4*)(Amat + (size_t)(base + e) * RANK);
    #pragma unroll
    for (int q = 0; q < 4; ++q) {
      f32x4 ar = Ar[q];
      #pragma unroll
      for (int j = 0; j < 4; ++j) {
        pa[q*4+j] += av[e] * ar[j];
        ph[q*4+j] += hv[e] * ar[j];
      }
    }
  }
  #pragma unroll
  for (int r = 0; r < RANK; ++r) {
    #pragma unroll
    for (int off = 32; off > 0; off >>= 1) {
      pa[r] += __shfl_xor(pa[r], off, 64);
      ph[r] += __shfl_xor(ph[r], off, 64);
    }
  }
  if (lane == 0) {
    #pragma unroll
    for (int r = 0; r < RANK; ++r) { redp[wv][r] = pa[r]; redh[wv][r] = ph[r]; }
  }
  __syncthreads();
  if (tid < RANK) {
    float sp = redp[0][tid] + redp[1][tid] + redp[2][tid] + redp[3][tid];
    float sh = redh[0][tid] + redh[1][tid] + redh[2][tid] + redh[3][tid];
    cmat[(size_t)token * RANK + tid] = sh * (MOD_SCALE * tanhf(sp));
  }
}

// ---------------------------------------------------------------------------
// Kernel 2: dual GEMM, 256x128 tile, BK=64, 8 waves (2M x 4N).
// R2 structure: ONE barrier per K-step. Body: {stage(t+1)->nxt; ds_reads(t);
// 64 MFMA; vmcnt(0) [pre-landed: stage(t+1) had a full MFMA cluster to fly];
// s_barrier}. No mid-phase barriers -> compiler interleaves af-odd ds_reads
// into the even MFMA cluster (LDS || MFMA overlap the phase structure forbade).
// XCD mapping: XCD x owns m-tiles {2x,2x+1} -> its 2 A-panels (2 MB) stay
// L2-resident for the whole kernel; concurrent window shares 2 B-panels.
// ---------------------------------------------------------------------------
#define BGOFF 16384
#define BUOFF 24576

__global__ __launch_bounds__(512, 2) void gemm_gateup(
    const _Float16* __restrict__ h16,
    const _Float16* __restrict__ Wg16, const _Float16* __restrict__ Wu16,
    const float* __restrict__ cmat, const float* __restrict__ Bmat,
    _Float16* __restrict__ tmat)
{
  __shared__ __align__(16) _Float16 lds[2][32768];   // 128 KB

  const int tid  = threadIdx.x;
  const int lane = tid & 63;
  const int wv   = tid >> 6;          // 0..7
  const int lr   = lane & 15;
  const int quad = lane >> 4;
  const int qb   = (wv >> 2) * 2;     // A quarter base: 0 or 2
  const int e    = wv & 3;            // B sub-tile (32 cols)
  const int wm   = (wv >> 2) * 128;   // wave row base in tile

  // XCD-partitioned mapping (native dispatch: lin%8 -> XCD):
  // xcd owns m-tiles {2*xcd, 2*xcd+1}; within-XCD order n-fast, m-pair inner.
  const int lin  = blockIdx.x;
  const int xcd  = lin & 7;
  const int r    = lin >> 3;                 // 0..127
  const int gm0  = (xcd * 2 + (r & 1)) * 256;
  const int gn0  = (r >> 1) * 128;

  constexpr int NT = D_MODEL / 64;    // 32

  f32x4 accG[8][2], accU[8][2];
  #pragma unroll
  for (int i = 0; i < 8; ++i)
    #pragma unroll
    for (int j = 0; j < 2; ++j) {
      f32x4 z = {0.f, 0.f, 0.f, 0.f};
      accG[i][j] = z; accU[i][j] = z;
    }

#define STA(b,q,t)  stage_round(h16  + (size_t)(gm0 + (q)*64) * D_MODEL + (size_t)(t)*64, D_MODEL, &lds[b][(q)*4096], tid)
#define STBG(b,p,t) stage_round(Wg16 + (size_t)(gn0 + (p)*64) * D_MODEL + (size_t)(t)*64, D_MODEL, &lds[b][BGOFF + (p)*4096], tid)
#define STBU(b,p,t) stage_round(Wu16 + (size_t)(gn0 + (p)*64) * D_MODEL + (size_t)(t)*64, D_MODEL, &lds[b][BUOFF + (p)*4096], tid)
#define STAGE_ALL(b,t) do { STA(b,0,t); STA(b,1,t); STA(b,2,t); STA(b,3,t); \
                            STBG(b,0,t); STBG(b,1,t); STBU(b,0,t); STBU(b,1,t); } while (0)

  // Prologue: tile 0 staged and landed.
  STAGE_ALL(0, 0);
  VMW(0); BARM();

  for (int t = 0; t < NT; ++t) {
    const int cur = t & 1, nxt = cur ^ 1;
    const _Float16* A   = &lds[cur][0];
    const _Float16* Bgp = &lds[cur][BGOFF + e * 2048];
    const _Float16* Bup = &lds[cur][BUOFF + e * 2048];

    // Issue next tile's staging first: lands during this tile's MFMAs.
    // Safe: nxt's old data (t-1) was fully consumed before the previous BARM.
    if (t + 1 < NT) STAGE_ALL(nxt, t + 1);

    half8 bg[2][2], bu[2][2], af[4][2];
    #pragma unroll
    for (int inn = 0; inn < 2; ++inn)
      #pragma unroll
      for (int kk = 0; kk < 2; ++kk) {
        bg[inn][kk] = frag64(Bgp, inn*16 + lr, kk*4 + quad);
        bu[inn][kk] = frag64(Bup, inn*16 + lr, kk*4 + quad);
      }
    #pragma unroll
    for (int im = 0; im < 4; ++im)
      #pragma unroll
      for (int kk = 0; kk < 2; ++kk)
        af[im][kk] = frag64(A + (qb + 0) * 4096, im*16 + lr, kk*4 + quad);

    PRIO1();
    #pragma unroll
    for (int im = 0; im < 4; ++im)
      #pragma unroll
      for (int inn = 0; inn < 2; ++inn)
        #pragma unroll
        for (int kk = 0; kk < 2; ++kk) {
          accG[im][inn] = __builtin_amdgcn_mfma_f32_16x16x32_f16(af[im][kk], bg[inn][kk], accG[im][inn], 0, 0, 0);
          accU[im][inn] = __builtin_amdgcn_mfma_f32_16x16x32_f16(af[im][kk], bu[inn][kk], accU[im][inn], 0, 0, 0);
        }
    PRIO0();

    half8 ao[4][2];
    #pragma unroll
    for (int im = 0; im < 4; ++im)
      #pragma unroll
      for (int kk = 0; kk < 2; ++kk)
        ao[im][kk] = frag64(A + (qb + 1) * 4096, im*16 + lr, kk*4 + quad);

    PRIO1();
    #pragma unroll
    for (int im = 0; im < 4; ++im)
      #pragma unroll
      for (int inn = 0; inn < 2; ++inn)
        #pragma unroll
        for (int kk = 0; kk < 2; ++kk) {
          accG[4+im][inn] = __builtin_amdgcn_mfma_f32_16x16x32_f16(ao[im][kk], bg[inn][kk], accG[4+im][inn], 0, 0, 0);
          accU[4+im][inn] = __builtin_amdgcn_mfma_f32_16x16x32_f16(ao[im][kk], bu[inn][kk], accU[4+im][inn], 0, 0, 0);
        }
    PRIO0();

    // stage(t+1) had the whole MFMA cluster (~2.5-4k cyc >> HBM latency) to
    // land -> this wait is effectively free. Then the single barrier.
    VMW(0); BARM();
  }

  // ---- rank-16 delta folded in as one zero-padded K=32 MFMA step into accG ----
  __syncthreads();   // full drain; loop is done
  _Float16* l0 = &lds[0][0];
  for (int i = tid; i < 8192; i += 512) {           // cbuf [256][32]
    int m = i >> 5, k = i & 31;
    l0[i] = (k < RANK) ? (_Float16)cmat[(size_t)(gm0 + m) * RANK + k] : (_Float16)0.f;
  }
  for (int i = tid; i < 4096; i += 512) {           // bbuf [128][32]
    int f = i >> 5, k = i & 31;
    l0[8192 + i] = (k < RANK) ? (_Float16)Bmat[(size_t)k * D_FFN + gn0 + f] : (_Float16)0.f;
  }
  __syncthreads();
  #pragma unroll
  for (int ai = 0; ai < 8; ++ai) {
    half8 cf = *(const half8*)&l0[(wm + ai*16 + lr) * 32 + quad * 8];
    #pragma unroll
    for (int inn = 0; inn < 2; ++inn) {
      half8 bd = *(const half8*)&l0[8192 + (e*32 + inn*16 + lr) * 32 + quad * 8];
      accG[ai][inn] = __builtin_amdgcn_mfma_f32_16x16x32_f16(cf, bd, accG[ai][inn], 0, 0, 0);
    }
  }

  // ---- Epilogue: t = silu(gate) * up ----
  #pragma unroll
  for (int ai = 0; ai < 8; ++ai)
    #pragma unroll
    for (int inn = 0; inn < 2; ++inn) {
      const int grow = gm0 + wm + ai*16 + quad*4;
      const int gcol = gn0 + e*32 + inn*16 + lr;
      #pragma unroll
      for (int rr = 0; rr < 4; ++rr) {
        float g = accG[ai][inn][rr];
        float u = accU[ai][inn][rr];
        float s = g / (1.0f + __expf(-g));
        tmat[(size_t)(grow + rr) * D_FFN + gcol] = (_Float16)(s * u);
      }
    }
#undef STA
#undef STBG
#undef STBU
#undef STAGE_ALL
}

// ---------------------------------------------------------------------------
// Kernel 3: out = hidden_states + t @ Wd16^T (K=8192). 256x128 tile, BK=64,
// 3-buffer rotation, 2-ahead staging, ONE barrier + counted vmcnt(6) per
// K-step (stage(t+2) stays in flight across the barrier; never drained to 0
// while t+2<NT). XCD mapping: XCD x owns n-tiles {2x,2x+1} -> its 2 Wd-panels
// (4 MB) L2-resident; each tmat panel shared by its 2 concurrent n-blocks.
// Grid = exactly 256 blocks (1 per CU).
// ---------------------------------------------------------------------------
__global__ __launch_bounds__(512, 2) void gemm_down(
    const _Float16* __restrict__ tmat, const _Float16* __restrict__ Wd16,
    const float* __restrict__ hs, float* __restrict__ out)
{
  __shared__ __align__(16) _Float16 lds[3][24576];   // 144 KB: A 16K halves | B 8K halves

  const int tid  = threadIdx.x;
  const int lane = tid & 63;
  const int wv   = tid >> 6;
  const int lr   = lane & 15;
  const int quad = lane >> 4;
  const int qb   = (wv >> 2) * 2;
  const int e    = wv & 3;
  const int wm   = (wv >> 2) * 128;

  const int lin  = blockIdx.x;               // 256 blocks
  const int xcd  = lin & 7;
  const int r    = lin >> 3;                 // 0..31
  const int gn0  = (xcd * 2 + (r & 1)) * 128;
  const int gm0  = (r >> 1) * 256;

  constexpr int NT = D_FFN / 64;          // 128

  f32x4 acc[8][2];
  #pragma unroll
  for (int i = 0; i < 8; ++i)
    #pragma unroll
    for (int j = 0; j < 2; ++j) {
      f32x4 z = {0.f, 0.f, 0.f, 0.f};
      acc[i][j] = z;
    }

#define DSTA(b,q,t) stage_round(tmat + (size_t)(gm0 + (q)*64) * D_FFN + (size_t)(t)*64, D_FFN, &lds[b][(q)*4096], tid)
#define DSTB(b,p,t) stage_round(Wd16 + (size_t)(gn0 + (p)*64) * D_FFN + (size_t)(t)*64, D_FFN, &lds[b][16384 + (p)*4096], tid)
#define DSTAGE_ALL(b,t) do { DSTA(b,0,t); DSTA(b,1,t); DSTA(b,2,t); DSTA(b,3,t); \
                             DSTB(b,0,t); DSTB(b,1,t); } while (0)

  // Prologue: tiles 0,1; wait to 6 -> tile 0 landed, tile 1 in flight.
  DSTAGE_ALL(0, 0);
  DSTAGE_ALL(1, 1);
  VMW(6); BARM();

  int cur = 0;
  for (int t = 0; t < NT; ++t) {
    const _Float16* A = &lds[cur][0];
    const _Float16* B = &lds[cur][16384 + e * 2048];
    int nx2 = cur + 2; if (nx2 >= 3) nx2 -= 3;     // buffer for tile t+2

    // 2-ahead staging into a buffer whose old data (t-1) was consumed before
    // the previous BARM.
    if (t + 2 < NT) DSTAGE_ALL(nx2, t + 2);

    half8 bf[2][2], af[4][2];
    #pragma unroll
    for (int inn = 0; inn < 2; ++inn)
      #pragma unroll
      for (int kk = 0; kk < 2; ++kk)
        bf[inn][kk] = frag64(B, inn*16 + lr, kk*4 + quad);
    #pragma unroll
    for (int im = 0; im < 4; ++im)
      #pragma unroll
      for (int kk = 0; kk < 2; ++kk)
        af[im][kk] = frag64(A + (qb + 0) * 4096, im*16 + lr, kk*4 + quad);

    PRIO1();
    #pragma unroll
    for (int im = 0; im < 4; ++im)
      #pragma unroll
      for (int inn = 0; inn < 2; ++inn)
        #pragma unroll
        for (int kk = 0; kk < 2; ++kk)
          acc[im][inn] = __builtin_amdgcn_mfma_f32_16x16x32_f16(af[im][kk], bf[inn][kk], acc[im][inn], 0, 0, 0);
    PRIO0();

    half8 ao[4][2];
    #pragma unroll
    for (int im = 0; im < 4; ++im)
      #pragma unroll
      for (int kk = 0; kk < 2; ++kk)
        ao[im][kk] = frag64(A + (qb + 1) * 4096, im*16 + lr, kk*4 + quad);

    PRIO1();
    #pragma unroll
    for (int im = 0; im < 4; ++im)
      #pragma unroll
      for (int inn = 0; inn < 2; ++inn)
        #pragma unroll
        for (int kk = 0; kk < 2; ++kk)
          acc[4+im][inn] = __builtin_amdgcn_mfma_f32_16x16x32_f16(ao[im][kk], bf[inn][kk], acc[4+im][inn], 0, 0, 0);
    PRIO0();

    // Drain stage(t+1) (needed next step); keep stage(t+2) in flight.
    if (t + 2 < NT) { VMW(6); } else { VMW(0); }
    BARM();

    cur += 1; if (cur >= 3) cur -= 3;
  }

  #pragma unroll
  for (int ai = 0; ai < 8; ++ai)
    #pragma unroll
    for (int inn = 0; inn < 2; ++inn) {
      const int grow = gm0 + wm + ai*16 + quad*4;
      const int gcol = gn0 + e*32 + inn*16 + lr;
      #pragma unroll
      for (int rr = 0; rr < 4; ++rr) {
        size_t o = (size_t)(grow + rr) * D_MODEL + gcol;
        out[o] = hs[o] + acc[ai][inn][rr];
      }
    }
#undef DSTA
#undef DSTB
#undef DSTAGE_ALL
}

extern "C" void kernel_launch(void* const* d_in, const int* in_sizes, int n_in,
                              void* d_out, int out_size, void* d_ws, size_t ws_size,
                              hipStream_t stream) {
  const float* hs    = (const float*)d_in[0];
  const float* attn  = (const float*)d_in[1];
  const float* Amat  = (const float*)d_in[2];
  const float* Bmat  = (const float*)d_in[3];
  const float* Wg    = (const float*)d_in[4];
  const float* Wu    = (const float*)d_in[5];
  const float* Wd    = (const float*)d_in[6];
  const float* gamma = (const float*)d_in[7];
  float* out = (float*)d_out;

  const int M = in_sizes[0] / D_MODEL;        // 4096 tokens
  const size_t WD = (size_t)D_FFN * D_MODEL;  // elements per big weight

  char* ws = (char*)d_ws;
  _Float16* h16  = (_Float16*)ws;
  float*    cmat = (float*)(ws + (size_t)M * D_MODEL * 2);
  _Float16* tmat = (_Float16*)(ws + (size_t)M * D_MODEL * 2 + (size_t)M * RANK * 4);
  _Float16* wbuf = tmat + (size_t)M * D_FFN;
  _Float16* Wg16 = wbuf;
  _Float16* Wu16 = wbuf + WD;

  const size_t base_bytes = (size_t)M * D_MODEL * 2 + (size_t)M * RANK * 4
                          + (size_t)M * D_FFN * 2 + 2 * WD * 2;
  const bool sep_wd = (ws_size >= base_bytes + WD * 2);
  _Float16* Wd16 = sep_wd ? (wbuf + 2 * WD) : wbuf;   // else reuse Wg16 slot

  const int convBlocks = (int)(WD / (256 * 8));   // 8192 per weight

  prep_kernel<<<M, 256, 0, stream>>>(hs, attn, Amat, gamma, h16, cmat);
  if (sep_wd) {
    convert3_f32_f16<<<3 * convBlocks, 256, 0, stream>>>(Wg, Wu, Wd, Wg16, Wu16, Wd16);
    gemm_gateup<<<dim3((D_FFN / 128) * (M / 256)), 512, 0, stream>>>(h16, Wg16, Wu16, cmat, Bmat, tmat);
  } else {
    convert_f32_f16<<<convBlocks, 256, 0, stream>>>(Wg, Wg16);
    convert_f32_f16<<<convBlocks, 256, 0, stream>>>(Wu, Wu16);
    gemm_gateup<<<dim3((D_FFN / 128) * (M / 256)), 512, 0, stream>>>(h16, Wg16, Wu16, cmat, Bmat, tmat);
    convert_f32_f16<<<convBlocks, 256, 0, stream>>>(Wd, Wd16);
  }
  gemm_down<<<dim3((D_MODEL / 128) * (M / 256)), 512, 0, stream>>>(tmat, Wd16, hs, out);
}